// Round 1
// baseline (1279.166 us; speedup 1.0000x reference)
//
#include <hip/hip_runtime.h>
#include <math.h>

#define BOX 128
#define MCELLS (BOX*BOX*BOX)

// ---------------------------------------------------------------------------
// Stage A: eps channels. One block per (batch, spec, atom). Each block
// scatters log1p(-rho) over the atom's 17^3 neighborhood with atomicAdd
// into the eps region of d_out (pre-zeroed). acc layout: (B, 4, 128^3).
// ---------------------------------------------------------------------------
__global__ __launch_bounds__(256) void eps_scatter_kernel(
    const float* __restrict__ coords,
    const float* __restrict__ params,
    const int* __restrict__ num_atoms,
    float* __restrict__ acc, int N) {
  int gid  = blockIdx.x;
  int atom = gid % N;
  int rest = gid / N;
  int spec = rest & 3;
  int b    = rest >> 2;
  if (atom >= num_atoms[b]) return;

  const float x = coords[(size_t)b * 3 * N + atom * 3 + 0];
  const float y = coords[(size_t)b * 3 * N + atom * 3 + 1];
  const float z = coords[(size_t)b * 3 * N + atom * 3 + 2];
  const float radius = params[((size_t)b * N + atom) * 2 + 1];

  const float offx  = (spec == 0) ? 0.5f : 0.0f;
  const float offy  = (spec == 1) ? 0.5f : 0.0f;
  const float offz  = (spec == 2) ? 0.5f : 0.0f;
  const float extra = (spec == 3) ? 1.0f : 1.4f;
  const float Reff  = radius + extra;

  // RES = 1.0: idx0 = round(xyz - offset), round-half-even matches jnp.round
  const int ix0 = (int)rintf(x - offx);
  const int iy0 = (int)rintf(y - offy);
  const int iz0 = (int)rintf(z - offz);

  float* __restrict__ g = acc + (size_t)(b * 4 + spec) * MCELLS;

  for (int t = threadIdx.x; t < 17 * 17 * 17; t += blockDim.x) {
    int oz = t % 17;
    int oy = (t / 17) % 17;
    int ox = t / (17 * 17);
    int ix = ix0 + ox - 8;
    int iy = iy0 + oy - 8;
    int iz = iz0 + oz - 8;
    if ((unsigned)ix >= (unsigned)BOX || (unsigned)iy >= (unsigned)BOX ||
        (unsigned)iz >= (unsigned)BOX) continue;
    float dx = ((float)ix + offx) - x;   // pos - xyz  (RES = 1)
    float dy = ((float)iy + offy) - y;
    float dz = ((float)iz + offz) - z;
    float r   = sqrtf(dx * dx + dy * dy + dz * dz + 1e-12f);
    float rho = 0.5f * (1.0f - erff((r - Reff) * 0.5f));  // ASIGMA = 2
    rho = fminf(fmaxf(rho, 0.0f), 1.0f - 1e-6f);
    float logv = log1pf(-rho);
    if (logv != 0.0f)  // adding exact +0.0f is a no-op; skip the atomic
      atomicAdd(&g[(ix * BOX + iy) * BOX + iz], logv);
  }
}

// ---------------------------------------------------------------------------
// Transform accumulated log-sums into eps, in place.
// channels 0..2: (1 - exp(acc))*(EPS_IN-EPS_OUT) + EPS_OUT = 6.5 + 72.5*exp(acc)
// channel  3   : 1 - exp(acc)
// ---------------------------------------------------------------------------
__global__ __launch_bounds__(256) void eps_finalize_kernel(
    float* __restrict__ eps, int total) {
  int i = blockIdx.x * blockDim.x + threadIdx.x;
  if (i >= total) return;
  int ch = (i / MCELLS) & 3;
  float v = expf(eps[i]);
  eps[i] = (ch < 3) ? fmaf(72.5f, v, 6.5f) : (1.0f - v);
}

// ---------------------------------------------------------------------------
// Stage B: trilinear charge scatter. One thread per (batch, atom).
// CHARGE_CONV folded into the charge (scatter is linear).
// ---------------------------------------------------------------------------
__global__ __launch_bounds__(256) void q_scatter_kernel(
    const float* __restrict__ coords,
    const float* __restrict__ params,
    const int* __restrict__ num_atoms,
    float* __restrict__ q, int N, int B) {
  int t = blockIdx.x * blockDim.x + threadIdx.x;
  if (t >= B * N) return;
  int b = t / N, atom = t % N;
  if (atom >= num_atoms[b]) return;

  const float x = coords[(size_t)b * 3 * N + atom * 3 + 0];
  const float y = coords[(size_t)b * 3 * N + atom * 3 + 1];
  const float z = coords[(size_t)b * 3 * N + atom * 3 + 2];
  const float c = params[((size_t)b * N + atom) * 2 + 0] * 7046.52f;

  float fx0 = floorf(x), fy0 = floorf(y), fz0 = floorf(z);
  int ix = (int)fx0, iy = (int)fy0, iz = (int)fz0;
  float fx = x - fx0, fy = y - fy0, fz = z - fz0;

  float* __restrict__ g = q + (size_t)b * MCELLS;
  for (int k = 0; k < 8; ++k) {
    int cx = (k >> 2) & 1, cy = (k >> 1) & 1, cz = k & 1;
    int jx = ix + cx, jy = iy + cy, jz = iz + cz;
    if ((unsigned)jx >= (unsigned)BOX || (unsigned)jy >= (unsigned)BOX ||
        (unsigned)jz >= (unsigned)BOX) continue;
    float w = (cx ? fx : 1.0f - fx) * (cy ? fy : 1.0f - fy) *
              (cz ? fz : 1.0f - fz);
    atomicAdd(&g[(jx * BOX + jy) * BOX + jz], w * c);
  }
}

// ---------------------------------------------------------------------------
// Stage C: one Jacobi sweep. 7-point variable-coefficient stencil.
// denom recomputed on the fly (needs only one extra load: lmbd).
// Shift semantics: exm[x] = ex[x-1] (0 at x=0); phi neighbors 0 out of bounds.
// ---------------------------------------------------------------------------
__global__ __launch_bounds__(256) void jacobi_kernel(
    const float* __restrict__ phi_in,
    float* __restrict__ phi_out,
    const float* __restrict__ eps,
    const float* __restrict__ rhs,   // = q (RES^2 = 1)
    int B) {
  int i = blockIdx.x * blockDim.x + threadIdx.x;
  if (i >= B * MCELLS) return;
  int b = i >> 21;            // MCELLS = 2^21
  int v = i & (MCELLS - 1);
  int z = v & 127;
  int y = (v >> 7) & 127;
  int x = v >> 14;

  const float* __restrict__ ex = eps + (size_t)(b * 4 + 0) * MCELLS;
  const float* __restrict__ ey = eps + (size_t)(b * 4 + 1) * MCELLS;
  const float* __restrict__ ez = eps + (size_t)(b * 4 + 2) * MCELLS;
  const float* __restrict__ lm = eps + (size_t)(b * 4 + 3) * MCELLS;
  const float* __restrict__ p  = phi_in + (size_t)b * MCELLS;

  float exc = ex[v], eyc = ey[v], ezc = ez[v];
  float exm = (x > 0) ? ex[v - BOX * BOX] : 0.0f;
  float eym = (y > 0) ? ey[v - BOX]       : 0.0f;
  float ezm = (z > 0) ? ez[v - 1]         : 0.0f;

  float num = rhs[i];
  num += (x < BOX - 1) ? exc * p[v + BOX * BOX] : 0.0f;
  num += (x > 0)       ? exm * p[v - BOX * BOX] : 0.0f;
  num += (y < BOX - 1) ? eyc * p[v + BOX]       : 0.0f;
  num += (y > 0)       ? eym * p[v - BOX]       : 0.0f;
  num += (z < BOX - 1) ? ezc * p[v + 1]         : 0.0f;
  num += (z > 0)       ? ezm * p[v - 1]         : 0.0f;

  float den = exc + exm + eyc + eym + ezc + ezm + 0.106f * lm[v];
  phi_out[i] = num / den;
}

// ---------------------------------------------------------------------------
extern "C" void kernel_launch(void* const* d_in, const int* in_sizes, int n_in,
                              void* d_out, int out_size, void* d_ws,
                              size_t ws_size, hipStream_t stream) {
  const float* coords    = (const float*)d_in[0];
  const float* params    = (const float*)d_in[1];
  const int*   num_atoms = (const int*)d_in[2];

  const int B = in_sizes[2];
  const int N = in_sizes[1] / (2 * B);

  float* out = (float*)d_out;
  float* q   = out;                            // (B, 128^3)
  float* eps = out + (size_t)B * MCELLS;       // (B, 4, 128^3)
  float* phi = out + (size_t)B * MCELLS * 5;   // (B, 128^3)
  float* ws_phi = (float*)d_ws;                // one 16 MB ping-pong buffer

  // Zero q, eps (scatter accumulators) and phi (Jacobi initial state).
  hipMemsetAsync(d_out, 0, sizeof(float) * (size_t)out_size, stream);

  // eps channels
  eps_scatter_kernel<<<B * 4 * N, 256, 0, stream>>>(coords, params, num_atoms,
                                                    eps, N);
  eps_finalize_kernel<<<(B * 4 * MCELLS + 255) / 256, 256, 0, stream>>>(
      eps, B * 4 * MCELLS);

  // charge grid (also the Jacobi RHS, since RES=1)
  q_scatter_kernel<<<(B * N + 255) / 256, 256, 0, stream>>>(
      coords, params, num_atoms, q, N, B);

  // 30 Jacobi sweeps; ping-pong out<->ws; 30 is even so final lands in out.
  float* pa = phi;     // holds phi_0 = 0
  float* pb = ws_phi;
  int total = B * MCELLS;
  for (int it = 0; it < 30; ++it) {
    jacobi_kernel<<<(total + 255) / 256, 256, 0, stream>>>(pa, pb, eps, q, B);
    float* tmp = pa; pa = pb; pb = tmp;
  }
  // result is in pa == phi (out)
}

// Round 2
// 1073.891 us; speedup vs baseline: 1.1912x; 1.1912x over previous
//
#include <hip/hip_runtime.h>
#include <math.h>

#define BOX 128
#define MCELLS (BOX*BOX*BOX)
typedef unsigned short u16;

__device__ __forceinline__ float bf2f(u16 h) {
  union { unsigned u; float f; } c; c.u = ((unsigned)h) << 16; return c.f;
}
__device__ __forceinline__ u16 f2bf(float f) {
  union { float f; unsigned u; } c; c.f = f;
  unsigned r = c.u + 0x7FFF + ((c.u >> 16) & 1);   // round-nearest-even
  return (u16)(r >> 16);
}

// ---------------------------------------------------------------------------
// Stage A: eps channels. One block per (batch, spec, atom); scatter
// log(0.5*(1+erf(u))) over the 17^3 neighborhood with atomicAdd.
// Fast path: A&S 7.1.26 erf (HW v_rcp + v_exp) + HW v_log; early-exit at
// u >= 3 (dropped contribution < 1.1e-5 per voxel).
// ---------------------------------------------------------------------------
__global__ __launch_bounds__(256) void eps_scatter_kernel(
    const float* __restrict__ coords,
    const float* __restrict__ params,
    const int* __restrict__ num_atoms,
    float* __restrict__ acc, int N) {
  int gid  = blockIdx.x;
  int atom = gid % N;
  int rest = gid / N;
  int spec = rest & 3;
  int b    = rest >> 2;
  if (atom >= num_atoms[b]) return;

  const float x = coords[(size_t)b * 3 * N + atom * 3 + 0];
  const float y = coords[(size_t)b * 3 * N + atom * 3 + 1];
  const float z = coords[(size_t)b * 3 * N + atom * 3 + 2];
  const float radius = params[((size_t)b * N + atom) * 2 + 1];

  const float offx  = (spec == 0) ? 0.5f : 0.0f;
  const float offy  = (spec == 1) ? 0.5f : 0.0f;
  const float offz  = (spec == 2) ? 0.5f : 0.0f;
  const float extra = (spec == 3) ? 1.0f : 1.4f;
  const float Reff  = radius + extra;
  const float rcut2 = (Reff + 6.0f) * (Reff + 6.0f);  // u >= 3 cutoff

  const int ix0 = (int)rintf(x - offx);
  const int iy0 = (int)rintf(y - offy);
  const int iz0 = (int)rintf(z - offz);

  float* __restrict__ g = acc + (size_t)(b * 4 + spec) * MCELLS;

  for (int t = threadIdx.x; t < 17 * 17 * 17; t += 256) {
    int oz = t % 17;
    int oy = (t / 17) % 17;
    int ox = t / (17 * 17);
    int ix = ix0 + ox - 8;
    int iy = iy0 + oy - 8;
    int iz = iz0 + oz - 8;
    if ((unsigned)ix >= (unsigned)BOX || (unsigned)iy >= (unsigned)BOX ||
        (unsigned)iz >= (unsigned)BOX) continue;
    float dx = ((float)ix + offx) - x;
    float dy = ((float)iy + offy) - y;
    float dz = ((float)iz + offz) - z;
    float r2 = dx * dx + dy * dy + dz * dz + 1e-12f;
    if (r2 >= rcut2) continue;
    float r = sqrtf(r2);
    float u = 0.5f * (r - Reff);
    // erf(|u|) via A&S 7.1.26 (abs err ~1.5e-7)
    float au = fabsf(u);
    float tt = __builtin_amdgcn_rcpf(fmaf(0.3275911f, au, 1.0f));
    float poly = tt * fmaf(tt, fmaf(tt, fmaf(tt, fmaf(tt, 1.061405429f,
                     -1.453152027f), 1.421413741f), -0.284496736f),
                     0.254829592f);
    float e = fmaf(-poly, __expf(-u * u), 1.0f);
    float erfu = (u < 0.0f) ? -e : e;
    float s = fmaf(0.5f, erfu, 0.5f);        // = 1 - rho
    s = fminf(fmaxf(s, 1e-6f), 1.0f);        // reference clip semantics
    float logv = __logf(s);
    atomicAdd(&g[(ix * BOX + iy) * BOX + iz], logv);
  }
}

// ---------------------------------------------------------------------------
// Fused: finalize eps in place (fp32, output) + pack bf16 copy for Jacobi.
// 4 cells per thread.
// ---------------------------------------------------------------------------
__global__ __launch_bounds__(256) void finalize_pack_kernel(
    float* __restrict__ eps, u16* __restrict__ ebf, int total4) {
  int t = blockIdx.x * 256 + threadIdx.x;
  if (t >= total4) return;
  int ch = (t / (MCELLS / 4)) & 3;
  float4 a = ((const float4*)eps)[t];
  float4 o;
  float v0 = __expf(a.x), v1 = __expf(a.y), v2 = __expf(a.z), v3 = __expf(a.w);
  if (ch < 3) {
    o.x = fmaf(72.5f, v0, 6.5f); o.y = fmaf(72.5f, v1, 6.5f);
    o.z = fmaf(72.5f, v2, 6.5f); o.w = fmaf(72.5f, v3, 6.5f);
  } else {
    o.x = 1.0f - v0; o.y = 1.0f - v1; o.z = 1.0f - v2; o.w = 1.0f - v3;
  }
  ((float4*)eps)[t] = o;
  ushort4 h; h.x = f2bf(o.x); h.y = f2bf(o.y); h.z = f2bf(o.z); h.w = f2bf(o.w);
  ((ushort4*)ebf)[t] = h;
}

__global__ __launch_bounds__(256) void rhs_pack_kernel(
    const float* __restrict__ q, u16* __restrict__ rbf, int total4) {
  int t = blockIdx.x * 256 + threadIdx.x;
  if (t >= total4) return;
  float4 a = ((const float4*)q)[t];
  ushort4 h; h.x = f2bf(a.x); h.y = f2bf(a.y); h.z = f2bf(a.z); h.w = f2bf(a.w);
  ((ushort4*)rbf)[t] = h;
}

// ---------------------------------------------------------------------------
// Fallback finalize (fp32 path)
// ---------------------------------------------------------------------------
__global__ __launch_bounds__(256) void eps_finalize_kernel(
    float* __restrict__ eps, int total) {
  int i = blockIdx.x * blockDim.x + threadIdx.x;
  if (i >= total) return;
  int ch = (i / MCELLS) & 3;
  float v = __expf(eps[i]);
  eps[i] = (ch < 3) ? fmaf(72.5f, v, 6.5f) : (1.0f - v);
}

// ---------------------------------------------------------------------------
// Stage B: trilinear charge scatter (CHARGE_CONV folded in).
// ---------------------------------------------------------------------------
__global__ __launch_bounds__(256) void q_scatter_kernel(
    const float* __restrict__ coords,
    const float* __restrict__ params,
    const int* __restrict__ num_atoms,
    float* __restrict__ q, int N, int B) {
  int t = blockIdx.x * blockDim.x + threadIdx.x;
  if (t >= B * N) return;
  int b = t / N, atom = t % N;
  if (atom >= num_atoms[b]) return;

  const float x = coords[(size_t)b * 3 * N + atom * 3 + 0];
  const float y = coords[(size_t)b * 3 * N + atom * 3 + 1];
  const float z = coords[(size_t)b * 3 * N + atom * 3 + 2];
  const float c = params[((size_t)b * N + atom) * 2 + 0] * 7046.52f;

  float fx0 = floorf(x), fy0 = floorf(y), fz0 = floorf(z);
  int ix = (int)fx0, iy = (int)fy0, iz = (int)fz0;
  float fx = x - fx0, fy = y - fy0, fz = z - fz0;

  float* __restrict__ g = q + (size_t)b * MCELLS;
  for (int k = 0; k < 8; ++k) {
    int cx = (k >> 2) & 1, cy = (k >> 1) & 1, cz = k & 1;
    int jx = ix + cx, jy = iy + cy, jz = iz + cz;
    if ((unsigned)jx >= (unsigned)BOX || (unsigned)jy >= (unsigned)BOX ||
        (unsigned)jz >= (unsigned)BOX) continue;
    float w = (cx ? fx : 1.0f - fx) * (cy ? fy : 1.0f - fy) *
              (cz ? fz : 1.0f - fz);
    atomicAdd(&g[(jx * BOX + jy) * BOX + jz], w * c);
  }
}

// ---------------------------------------------------------------------------
// Stage C (bf16 path): first sweep, phi==0 so phi' = rhs/den. No phi reads.
// ---------------------------------------------------------------------------
__global__ __launch_bounds__(256) void jacobi0_kernel(
    float* __restrict__ phi_out,
    const u16* __restrict__ ebf, const u16* __restrict__ rbf, int B) {
  int per_b = MCELLS / 4;
  int t = blockIdx.x * 256 + threadIdx.x;
  if (t >= B * per_b) return;
  int b  = t / per_b;
  int r  = t - b * per_b;
  int zg = r & 31;
  int y  = (r >> 5) & 127;
  int x  = r >> 12;
  int z0 = zg << 2;
  int v  = (x << 14) + (y << 7) + z0;

  const u16* __restrict__ ex = ebf + (size_t)(b * 4 + 0) * MCELLS;
  const u16* __restrict__ ey = ebf + (size_t)(b * 4 + 1) * MCELLS;
  const u16* __restrict__ ez = ebf + (size_t)(b * 4 + 2) * MCELLS;
  const u16* __restrict__ lm = ebf + (size_t)(b * 4 + 3) * MCELLS;
  const u16* __restrict__ rq = rbf + (size_t)b * MCELLS;

  const ushort4 zu = make_ushort4(0, 0, 0, 0);
  ushort4 exc = ((const ushort4*)(ex + v))[0];
  ushort4 eyc = ((const ushort4*)(ey + v))[0];
  ushort4 ezc = ((const ushort4*)(ez + v))[0];
  ushort4 lmc = ((const ushort4*)(lm + v))[0];
  ushort4 rqc = ((const ushort4*)(rq + v))[0];
  ushort4 exm = (x > 0) ? ((const ushort4*)(ex + v - 16384))[0] : zu;
  ushort4 eym = (y > 0) ? ((const ushort4*)(ey + v - 128))[0] : zu;
  u16 ezA[5];
  ezA[0] = (z0 > 0) ? ez[v - 1] : (u16)0;
  ezA[1] = ezc.x; ezA[2] = ezc.y; ezA[3] = ezc.z; ezA[4] = ezc.w;

  float excA[4] = {bf2f(exc.x), bf2f(exc.y), bf2f(exc.z), bf2f(exc.w)};
  float exmA[4] = {bf2f(exm.x), bf2f(exm.y), bf2f(exm.z), bf2f(exm.w)};
  float eycA[4] = {bf2f(eyc.x), bf2f(eyc.y), bf2f(eyc.z), bf2f(eyc.w)};
  float eymA[4] = {bf2f(eym.x), bf2f(eym.y), bf2f(eym.z), bf2f(eym.w)};
  float lmA[4]  = {bf2f(lmc.x), bf2f(lmc.y), bf2f(lmc.z), bf2f(lmc.w)};
  float rqA[4]  = {bf2f(rqc.x), bf2f(rqc.y), bf2f(rqc.z), bf2f(rqc.w)};

  float o[4];
#pragma unroll
  for (int i = 0; i < 4; ++i) {
    float den = excA[i] + exmA[i] + eycA[i] + eymA[i] + bf2f(ezA[i + 1]) +
                bf2f(ezA[i]) + 0.106f * lmA[i];
    o[i] = rqA[i] * __builtin_amdgcn_rcpf(den);
  }
  ((float4*)(phi_out + (size_t)b * MCELLS + v))[0] =
      make_float4(o[0], o[1], o[2], o[3]);
}

// ---------------------------------------------------------------------------
// Stage C (bf16 path): main sweep, 4 cells/thread along z.
// ---------------------------------------------------------------------------
__global__ __launch_bounds__(256) void jacobi_bf16_kernel(
    const float* __restrict__ phi_in, float* __restrict__ phi_out,
    const u16* __restrict__ ebf, const u16* __restrict__ rbf, int B) {
  int per_b = MCELLS / 4;
  int t = blockIdx.x * 256 + threadIdx.x;
  if (t >= B * per_b) return;
  int b  = t / per_b;
  int r  = t - b * per_b;
  int zg = r & 31;
  int y  = (r >> 5) & 127;
  int x  = r >> 12;
  int z0 = zg << 2;
  int v  = (x << 14) + (y << 7) + z0;

  const u16* __restrict__ ex = ebf + (size_t)(b * 4 + 0) * MCELLS;
  const u16* __restrict__ ey = ebf + (size_t)(b * 4 + 1) * MCELLS;
  const u16* __restrict__ ez = ebf + (size_t)(b * 4 + 2) * MCELLS;
  const u16* __restrict__ lm = ebf + (size_t)(b * 4 + 3) * MCELLS;
  const u16* __restrict__ rq = rbf + (size_t)b * MCELLS;
  const float* __restrict__ p = phi_in + (size_t)b * MCELLS;

  float4 pc = ((const float4*)(p + v))[0];
  float pA[6];
  pA[0] = (z0 > 0)   ? p[v - 1] : 0.0f;
  pA[1] = pc.x; pA[2] = pc.y; pA[3] = pc.z; pA[4] = pc.w;
  pA[5] = (z0 < 124) ? p[v + 4] : 0.0f;

  const float4 zf = make_float4(0, 0, 0, 0);
  float4 xp = (x < 127) ? ((const float4*)(p + v + 16384))[0] : zf;
  float4 xm = (x > 0)   ? ((const float4*)(p + v - 16384))[0] : zf;
  float4 yp = (y < 127) ? ((const float4*)(p + v + 128))[0] : zf;
  float4 ym = (y > 0)   ? ((const float4*)(p + v - 128))[0] : zf;

  const ushort4 zu = make_ushort4(0, 0, 0, 0);
  ushort4 exc = ((const ushort4*)(ex + v))[0];
  ushort4 eyc = ((const ushort4*)(ey + v))[0];
  ushort4 ezc = ((const ushort4*)(ez + v))[0];
  ushort4 lmc = ((const ushort4*)(lm + v))[0];
  ushort4 rqc = ((const ushort4*)(rq + v))[0];
  ushort4 exm = (x > 0) ? ((const ushort4*)(ex + v - 16384))[0] : zu;
  ushort4 eym = (y > 0) ? ((const ushort4*)(ey + v - 128))[0] : zu;
  u16 ezA[5];
  ezA[0] = (z0 > 0) ? ez[v - 1] : (u16)0;
  ezA[1] = ezc.x; ezA[2] = ezc.y; ezA[3] = ezc.z; ezA[4] = ezc.w;

  float excA[4] = {bf2f(exc.x), bf2f(exc.y), bf2f(exc.z), bf2f(exc.w)};
  float exmA[4] = {bf2f(exm.x), bf2f(exm.y), bf2f(exm.z), bf2f(exm.w)};
  float eycA[4] = {bf2f(eyc.x), bf2f(eyc.y), bf2f(eyc.z), bf2f(eyc.w)};
  float eymA[4] = {bf2f(eym.x), bf2f(eym.y), bf2f(eym.z), bf2f(eym.w)};
  float lmA[4]  = {bf2f(lmc.x), bf2f(lmc.y), bf2f(lmc.z), bf2f(lmc.w)};
  float rqA[4]  = {bf2f(rqc.x), bf2f(rqc.y), bf2f(rqc.z), bf2f(rqc.w)};
  float xpA[4] = {xp.x, xp.y, xp.z, xp.w};
  float xmA[4] = {xm.x, xm.y, xm.z, xm.w};
  float ypA[4] = {yp.x, yp.y, yp.z, yp.w};
  float ymA[4] = {ym.x, ym.y, ym.z, ym.w};

  float o[4];
#pragma unroll
  for (int i = 0; i < 4; ++i) {
    float ezci = bf2f(ezA[i + 1]), ezmi = bf2f(ezA[i]);
    float num = rqA[i];
    num = fmaf(excA[i], xpA[i], num);
    num = fmaf(exmA[i], xmA[i], num);
    num = fmaf(eycA[i], ypA[i], num);
    num = fmaf(eymA[i], ymA[i], num);
    num = fmaf(ezci, pA[i + 2], num);
    num = fmaf(ezmi, pA[i], num);
    float den = excA[i] + exmA[i] + eycA[i] + eymA[i] + ezci + ezmi +
                0.106f * lmA[i];
    o[i] = num * __builtin_amdgcn_rcpf(den);
  }
  ((float4*)(phi_out + (size_t)b * MCELLS + v))[0] =
      make_float4(o[0], o[1], o[2], o[3]);
}

// ---------------------------------------------------------------------------
// Fallback fp32 Jacobi (if ws too small for bf16 arrays)
// ---------------------------------------------------------------------------
__global__ __launch_bounds__(256) void jacobi_kernel(
    const float* __restrict__ phi_in, float* __restrict__ phi_out,
    const float* __restrict__ eps, const float* __restrict__ rhs, int B) {
  int i = blockIdx.x * blockDim.x + threadIdx.x;
  if (i >= B * MCELLS) return;
  int b = i >> 21;
  int v = i & (MCELLS - 1);
  int z = v & 127;
  int y = (v >> 7) & 127;
  int x = v >> 14;

  const float* __restrict__ ex = eps + (size_t)(b * 4 + 0) * MCELLS;
  const float* __restrict__ ey = eps + (size_t)(b * 4 + 1) * MCELLS;
  const float* __restrict__ ez = eps + (size_t)(b * 4 + 2) * MCELLS;
  const float* __restrict__ lm = eps + (size_t)(b * 4 + 3) * MCELLS;
  const float* __restrict__ p  = phi_in + (size_t)b * MCELLS;

  float exc = ex[v], eyc = ey[v], ezc = ez[v];
  float exm = (x > 0) ? ex[v - BOX * BOX] : 0.0f;
  float eym = (y > 0) ? ey[v - BOX]       : 0.0f;
  float ezm = (z > 0) ? ez[v - 1]         : 0.0f;

  float num = rhs[i];
  num += (x < BOX - 1) ? exc * p[v + BOX * BOX] : 0.0f;
  num += (x > 0)       ? exm * p[v - BOX * BOX] : 0.0f;
  num += (y < BOX - 1) ? eyc * p[v + BOX]       : 0.0f;
  num += (y > 0)       ? eym * p[v - BOX]       : 0.0f;
  num += (z < BOX - 1) ? ezc * p[v + 1]         : 0.0f;
  num += (z > 0)       ? ezm * p[v - 1]         : 0.0f;

  float den = exc + exm + eyc + eym + ezc + ezm + 0.106f * lm[v];
  phi_out[i] = num / den;
}

// ---------------------------------------------------------------------------
extern "C" void kernel_launch(void* const* d_in, const int* in_sizes, int n_in,
                              void* d_out, int out_size, void* d_ws,
                              size_t ws_size, hipStream_t stream) {
  const float* coords    = (const float*)d_in[0];
  const float* params    = (const float*)d_in[1];
  const int*   num_atoms = (const int*)d_in[2];

  const int B = in_sizes[2];
  const int N = in_sizes[1] / (2 * B);

  float* out = (float*)d_out;
  float* q   = out;                            // (B, M)
  float* eps = out + (size_t)B * MCELLS;       // (B, 4, M)
  float* phi = out + (size_t)B * MCELLS * 5;   // (B, M)

  // Zero only the scatter accumulators (q + eps); phi is fully overwritten.
  hipMemsetAsync(d_out, 0, sizeof(float) * (size_t)B * MCELLS * 5, stream);

  eps_scatter_kernel<<<B * 4 * N, 256, 0, stream>>>(coords, params, num_atoms,
                                                    eps, N);
  q_scatter_kernel<<<(B * N + 255) / 256, 256, 0, stream>>>(
      coords, params, num_atoms, q, N, B);

  size_t need = (size_t)B * MCELLS * 4      // ws phi ping buffer
              + (size_t)B * 4 * MCELLS * 2  // bf16 eps
              + (size_t)B * MCELLS * 2;     // bf16 rhs

  if (ws_size >= need) {
    float* ws_phi = (float*)d_ws;
    u16* ebf = (u16*)((char*)d_ws + (size_t)B * MCELLS * 4);
    u16* rbf = ebf + (size_t)B * 4 * MCELLS;

    int e4 = B * 4 * MCELLS / 4;
    finalize_pack_kernel<<<(e4 + 255) / 256, 256, 0, stream>>>(eps, ebf, e4);
    int q4 = B * MCELLS / 4;
    rhs_pack_kernel<<<(q4 + 255) / 256, 256, 0, stream>>>(q, rbf, q4);

    int t4 = B * MCELLS / 4;
    int blocks = (t4 + 255) / 256;
    // 30 sweeps total: jacobi0 writes ws; odd iters write out-phi; iter 29
    // (the 30th sweep) lands in out-phi.
    jacobi0_kernel<<<blocks, 256, 0, stream>>>(ws_phi, ebf, rbf, B);
    float* pa = ws_phi;
    float* pb = phi;
    for (int it = 1; it < 30; ++it) {
      jacobi_bf16_kernel<<<blocks, 256, 0, stream>>>(pa, pb, ebf, rbf, B);
      float* tmp = pa; pa = pb; pb = tmp;
    }
  } else {
    // fp32 fallback
    eps_finalize_kernel<<<(B * 4 * MCELLS + 255) / 256, 256, 0, stream>>>(
        eps, B * 4 * MCELLS);
    hipMemsetAsync(phi, 0, sizeof(float) * (size_t)B * MCELLS, stream);
    float* pa = phi;
    float* pb = (float*)d_ws;
    int total = B * MCELLS;
    for (int it = 0; it < 30; ++it) {
      jacobi_kernel<<<(total + 255) / 256, 256, 0, stream>>>(pa, pb, eps, q, B);
      float* tmp = pa; pa = pb; pb = tmp;
    }
  }
}

// Round 3
// 951.205 us; speedup vs baseline: 1.3448x; 1.1290x over previous
//
#include <hip/hip_runtime.h>
#include <math.h>

#define BOX 128
#define MCELLS (BOX*BOX*BOX)
typedef unsigned short u16;

__device__ __forceinline__ float bf2f(u16 h) {
  union { unsigned u; float f; } c; c.u = ((unsigned)h) << 16; return c.f;
}
__device__ __forceinline__ u16 f2bf(float f) {
  union { float f; unsigned u; } c; c.f = f;
  unsigned r = c.u + 0x7FFF + ((c.u >> 16) & 1);   // round-nearest-even
  return (u16)(r >> 16);
}

// log(0.5*(1+erf(0.5*(r-R)))) via A&S 7.1.26 erf + HW exp/log
__device__ __forceinline__ float logterm(float r2, float R) {
  float r = sqrtf(r2 + 1e-12f);
  float u = 0.5f * (r - R);
  float au = fabsf(u);
  float tt = __builtin_amdgcn_rcpf(fmaf(0.3275911f, au, 1.0f));
  float poly = tt * fmaf(tt, fmaf(tt, fmaf(tt, fmaf(tt, 1.061405429f,
                   -1.453152027f), 1.421413741f), -0.284496736f),
                   0.254829592f);
  float e = fmaf(-poly, __expf(-u * u), 1.0f);
  float erfu = (u < 0.0f) ? -e : e;
  float s = fmaf(0.5f, erfu, 0.5f);   // = 1 - rho
  s = fminf(fmaxf(s, 1e-6f), 1.0f);   // reference clip semantics
  return __logf(s);
}

// ---------------------------------------------------------------------------
// Stage A (gather): one block per 8x8x16 voxel tile per batch. Cull all N
// atoms against the tile's expanded AABB into LDS, then each thread
// accumulates 4 voxels x 4 channels in registers. No atomics. Writes
// finalized fp32 eps to d_out and bf16 ex/ey/ez packs for the Jacobi.
// ---------------------------------------------------------------------------
__global__ __launch_bounds__(256) void eps_gather_kernel(
    const float* __restrict__ coords,
    const float* __restrict__ params,
    const int* __restrict__ num_atoms,
    float* __restrict__ eps_out,     // (B,4,M)
    u16* __restrict__ exb, u16* __restrict__ eyb, u16* __restrict__ ezb,
    int N) {
  __shared__ float4 sat[1024];
  __shared__ int scnt;

  const int xt = blockIdx.x, yt = blockIdx.y;
  const int bz = blockIdx.z;
  const int b  = bz >> 3;
  const int zt = bz & 7;
  const int tid = threadIdx.x;

  // sample positions span [lo, lo+T-1+0.5] (channel offsets add up to +0.5)
  const float lox = (float)(xt * 8),  hix = lox + 7.5f;
  const float loy = (float)(yt * 8),  hiy = loy + 7.5f;
  const float loz = (float)(zt * 16), hiz = loz + 15.5f;

  if (tid == 0) scnt = 0;
  __syncthreads();

  const int na = num_atoms[b];
  for (int a = tid; a < N; a += 256) {
    if (a < na) {
      float ax = coords[(size_t)b * 3 * N + a * 3 + 0];
      float ay = coords[(size_t)b * 3 * N + a * 3 + 1];
      float az = coords[(size_t)b * 3 * N + a * 3 + 2];
      float rad = params[((size_t)b * N + a) * 2 + 1];
      float cx = fminf(fmaxf(ax, lox), hix);
      float cy = fminf(fmaxf(ay, loy), hiy);
      float cz = fminf(fmaxf(az, loz), hiz);
      float ddx = ax - cx, ddy = ay - cy, ddz = az - cz;
      float cut = rad + 7.4f;                 // max Reff + 6 (u<3 cutoff)
      if (ddx * ddx + ddy * ddy + ddz * ddz < cut * cut) {
        int s = atomicAdd(&scnt, 1);
        if (s < 1024) sat[s] = make_float4(ax, ay, az, rad);
      }
    }
  }
  __syncthreads();
  const int cnt = min(scnt, 1024);

  const int zq = tid & 3, yy = (tid >> 2) & 7, xx = tid >> 5;
  const int xi = xt * 8 + xx, yi = yt * 8 + yy, z0 = zt * 16 + zq * 4;
  const float xf = (float)xi, yf = (float)yi, zf = (float)z0;

  float acc[4][4] = {{0.f}};

  for (int j = 0; j < cnt; ++j) {
    float4 A = sat[j];
    float dx = xf - A.x, dy = yf - A.y, dzb = zf - A.z;
    float Rw = A.w + 1.4f, Ri = A.w + 1.0f;
    float cw = Rw + 6.0f, ci = Ri + 6.0f;
    float cw2 = cw * cw, ci2 = ci * ci;

    float dx2 = dx * dx, dxh = dx + 0.5f, dxh2 = dxh * dxh;
    float dy2 = dy * dy, dyh = dy + 0.5f, dyh2 = dyh * dyh;

    // conservative per-atom prune over the 4-z strip and all channels
    float mdx = fminf(dx2, dxh2);
    float mdy = fminf(dy2, dyh2);
    float zhi = dzb + 3.5f;
    float mdz = (dzb > 0.f) ? dzb * dzb : (zhi < 0.f ? zhi * zhi : 0.f);
    if (mdx + mdy + mdz >= cw2) continue;

#pragma unroll
    for (int k = 0; k < 4; ++k) {
      float dzv = dzb + (float)k;
      float dz2 = dzv * dzv, dzh = dzv + 0.5f, dzh2 = dzh * dzh;
      float r0 = dxh2 + dy2 + dz2;
      if (r0 < cw2) acc[0][k] += logterm(r0, Rw);
      float r1 = dx2 + dyh2 + dz2;
      if (r1 < cw2) acc[1][k] += logterm(r1, Rw);
      float r2c = dx2 + dy2 + dzh2;
      if (r2c < cw2) acc[2][k] += logterm(r2c, Rw);
      float r3 = dx2 + dy2 + dz2;
      if (r3 < ci2) acc[3][k] += logterm(r3, Ri);
    }
  }

  const int v = (xi << 14) + (yi << 7) + z0;
  const size_t ebase = (size_t)b * 4 * MCELLS;

  float ev[4][4];
#pragma unroll
  for (int ch = 0; ch < 4; ++ch) {
#pragma unroll
    for (int k = 0; k < 4; ++k) {
      float vac = __expf(acc[ch][k]);
      ev[ch][k] = (ch < 3) ? fmaf(72.5f, vac, 6.5f) : (1.0f - vac);
    }
    ((float4*)(eps_out + ebase + (size_t)ch * MCELLS + v))[0] =
        make_float4(ev[ch][0], ev[ch][1], ev[ch][2], ev[ch][3]);
  }
  const size_t cb = (size_t)b * MCELLS + v;
  ((ushort4*)(exb + cb))[0] = make_ushort4(f2bf(ev[0][0]), f2bf(ev[0][1]),
                                           f2bf(ev[0][2]), f2bf(ev[0][3]));
  ((ushort4*)(eyb + cb))[0] = make_ushort4(f2bf(ev[1][0]), f2bf(ev[1][1]),
                                           f2bf(ev[1][2]), f2bf(ev[1][3]));
  ((ushort4*)(ezb + cb))[0] = make_ushort4(f2bf(ev[2][0]), f2bf(ev[2][1]),
                                           f2bf(ev[2][2]), f2bf(ev[2][3]));
}

// ---------------------------------------------------------------------------
// Stage B: trilinear charge scatter (CHARGE_CONV folded in).
// ---------------------------------------------------------------------------
__global__ __launch_bounds__(256) void q_scatter_kernel(
    const float* __restrict__ coords,
    const float* __restrict__ params,
    const int* __restrict__ num_atoms,
    float* __restrict__ q, int N, int B) {
  int t = blockIdx.x * blockDim.x + threadIdx.x;
  if (t >= B * N) return;
  int b = t / N, atom = t % N;
  if (atom >= num_atoms[b]) return;

  const float x = coords[(size_t)b * 3 * N + atom * 3 + 0];
  const float y = coords[(size_t)b * 3 * N + atom * 3 + 1];
  const float z = coords[(size_t)b * 3 * N + atom * 3 + 2];
  const float c = params[((size_t)b * N + atom) * 2 + 0] * 7046.52f;

  float fx0 = floorf(x), fy0 = floorf(y), fz0 = floorf(z);
  int ix = (int)fx0, iy = (int)fy0, iz = (int)fz0;
  float fx = x - fx0, fy = y - fy0, fz = z - fz0;

  float* __restrict__ g = q + (size_t)b * MCELLS;
  for (int k = 0; k < 8; ++k) {
    int cx = (k >> 2) & 1, cy = (k >> 1) & 1, cz = k & 1;
    int jx = ix + cx, jy = iy + cy, jz = iz + cz;
    if ((unsigned)jx >= (unsigned)BOX || (unsigned)jy >= (unsigned)BOX ||
        (unsigned)jz >= (unsigned)BOX) continue;
    float w = (cx ? fx : 1.0f - fx) * (cy ? fy : 1.0f - fy) *
              (cz ? fz : 1.0f - fz);
    atomicAdd(&g[(jx * BOX + jy) * BOX + jz], w * c);
  }
}

// ---------------------------------------------------------------------------
// Prep: rden = 1/den (bf16), rq2 = rhs*rden (bf16), phi1 = rq2 (bf16).
// den from fp32 eps in d_out (includes lambda); one-time pass.
// ---------------------------------------------------------------------------
__global__ __launch_bounds__(256) void prep_kernel(
    const float* __restrict__ eps,   // (B,4,M) fp32
    const float* __restrict__ q,
    u16* __restrict__ rdn, u16* __restrict__ rq2, u16* __restrict__ phiA,
    int B) {
  const int per_b = MCELLS / 4;
  int t = blockIdx.x * 256 + threadIdx.x;
  if (t >= B * per_b) return;
  int b = t / per_b;
  int r = t - b * per_b;
  int zg = r & 31, y = (r >> 5) & 127, x = r >> 12;
  int z0 = zg << 2;
  int v = (x << 14) + (y << 7) + z0;

  const float* ex = eps + (size_t)(b * 4 + 0) * MCELLS;
  const float* ey = eps + (size_t)(b * 4 + 1) * MCELLS;
  const float* ez = eps + (size_t)(b * 4 + 2) * MCELLS;
  const float* lm = eps + (size_t)(b * 4 + 3) * MCELLS;

  const float4 zf4 = make_float4(0, 0, 0, 0);
  float4 exc = ((const float4*)(ex + v))[0];
  float4 eyc = ((const float4*)(ey + v))[0];
  float4 ezc = ((const float4*)(ez + v))[0];
  float4 lmc = ((const float4*)(lm + v))[0];
  float4 qc  = ((const float4*)(q + (size_t)b * MCELLS + v))[0];
  float4 exm = (x > 0) ? ((const float4*)(ex + v - 16384))[0] : zf4;
  float4 eym = (y > 0) ? ((const float4*)(ey + v - 128))[0] : zf4;
  float ezmA[4];
  ezmA[0] = (z0 > 0) ? ez[v - 1] : 0.0f;
  ezmA[1] = ezc.x; ezmA[2] = ezc.y; ezmA[3] = ezc.z;

  float excA[4] = {exc.x, exc.y, exc.z, exc.w};
  float exmA[4] = {exm.x, exm.y, exm.z, exm.w};
  float eycA[4] = {eyc.x, eyc.y, eyc.z, eyc.w};
  float eymA[4] = {eym.x, eym.y, eym.z, eym.w};
  float ezcA[4] = {ezc.x, ezc.y, ezc.z, ezc.w};
  float lmA[4]  = {lmc.x, lmc.y, lmc.z, lmc.w};
  float qA[4]   = {qc.x, qc.y, qc.z, qc.w};

  ushort4 rd_o, rq_o;
  u16* rdp = (u16*)&rd_o; u16* rqp = (u16*)&rq_o;
#pragma unroll
  for (int i = 0; i < 4; ++i) {
    float den = excA[i] + exmA[i] + eycA[i] + eymA[i] + ezcA[i] + ezmA[i] +
                0.106f * lmA[i];
    float rd = __builtin_amdgcn_rcpf(den);
    rdp[i] = f2bf(rd);
    rqp[i] = f2bf(qA[i] * rd);
  }
  size_t cb = (size_t)b * MCELLS + v;
  ((ushort4*)(rdn + cb))[0] = rd_o;
  ((ushort4*)(rq2 + cb))[0] = rq_o;
  ((ushort4*)(phiA + cb))[0] = rq_o;   // phi after sweep 1 == rq2
}

// ---------------------------------------------------------------------------
// Jacobi sweep, all-bf16 inputs, 4 cells/thread. FINAL writes fp32 to out.
// phi' = rq2 + rden * (6-term stencil)
// ---------------------------------------------------------------------------
template <bool FINAL>
__global__ __launch_bounds__(256) void jacobi_sweep_kernel(
    const u16* __restrict__ pin, u16* __restrict__ pout,
    float* __restrict__ pout_f,
    const u16* __restrict__ exb, const u16* __restrict__ eyb,
    const u16* __restrict__ ezb, const u16* __restrict__ rdn,
    const u16* __restrict__ rq2, int B) {
  const int per_b = MCELLS / 4;
  int t = blockIdx.x * 256 + threadIdx.x;
  if (t >= B * per_b) return;
  int b = t / per_b;
  int r = t - b * per_b;
  int zg = r & 31, y = (r >> 5) & 127, x = r >> 12;
  int z0 = zg << 2;
  int v = (x << 14) + (y << 7) + z0;
  const size_t cb0 = (size_t)b * MCELLS;

  const u16* p = pin + cb0;
  const ushort4 zu = make_ushort4(0, 0, 0, 0);

  ushort4 pc = ((const ushort4*)(p + v))[0];
  u16 pzm = (z0 > 0)   ? p[v - 1] : (u16)0;
  u16 pzp = (z0 < 124) ? p[v + 4] : (u16)0;
  ushort4 pxp = (x < 127) ? ((const ushort4*)(p + v + 16384))[0] : zu;
  ushort4 pxm = (x > 0)   ? ((const ushort4*)(p + v - 16384))[0] : zu;
  ushort4 pyp = (y < 127) ? ((const ushort4*)(p + v + 128))[0] : zu;
  ushort4 pym = (y > 0)   ? ((const ushort4*)(p + v - 128))[0] : zu;

  ushort4 exc = ((const ushort4*)(exb + cb0 + v))[0];
  ushort4 eyc = ((const ushort4*)(eyb + cb0 + v))[0];
  ushort4 ezc = ((const ushort4*)(ezb + cb0 + v))[0];
  ushort4 rdc = ((const ushort4*)(rdn + cb0 + v))[0];
  ushort4 rqc = ((const ushort4*)(rq2 + cb0 + v))[0];
  ushort4 exm = (x > 0) ? ((const ushort4*)(exb + cb0 + v - 16384))[0] : zu;
  ushort4 eym = (y > 0) ? ((const ushort4*)(eyb + cb0 + v - 128))[0] : zu;
  u16 ezm0 = (z0 > 0) ? ezb[cb0 + v - 1] : (u16)0;

  // phi column: indices z0-1 .. z0+4
  float pz[6];
  pz[0] = bf2f(pzm);
  pz[1] = bf2f(pc.x); pz[2] = bf2f(pc.y); pz[3] = bf2f(pc.z); pz[4] = bf2f(pc.w);
  pz[5] = bf2f(pzp);
  // ez column: ezm for cell k is ez[z0+k-1]
  float ezA[5];
  ezA[0] = bf2f(ezm0);
  ezA[1] = bf2f(ezc.x); ezA[2] = bf2f(ezc.y); ezA[3] = bf2f(ezc.z);
  ezA[4] = bf2f(ezc.w);

  float excA[4] = {bf2f(exc.x), bf2f(exc.y), bf2f(exc.z), bf2f(exc.w)};
  float exmA[4] = {bf2f(exm.x), bf2f(exm.y), bf2f(exm.z), bf2f(exm.w)};
  float eycA[4] = {bf2f(eyc.x), bf2f(eyc.y), bf2f(eyc.z), bf2f(eyc.w)};
  float eymA[4] = {bf2f(eym.x), bf2f(eym.y), bf2f(eym.z), bf2f(eym.w)};
  float rdA[4]  = {bf2f(rdc.x), bf2f(rdc.y), bf2f(rdc.z), bf2f(rdc.w)};
  float rqA[4]  = {bf2f(rqc.x), bf2f(rqc.y), bf2f(rqc.z), bf2f(rqc.w)};
  float xpA[4] = {bf2f(pxp.x), bf2f(pxp.y), bf2f(pxp.z), bf2f(pxp.w)};
  float xmA[4] = {bf2f(pxm.x), bf2f(pxm.y), bf2f(pxm.z), bf2f(pxm.w)};
  float ypA[4] = {bf2f(pyp.x), bf2f(pyp.y), bf2f(pyp.z), bf2f(pyp.w)};
  float ymA[4] = {bf2f(pym.x), bf2f(pym.y), bf2f(pym.z), bf2f(pym.w)};

  float o[4];
#pragma unroll
  for (int i = 0; i < 4; ++i) {
    float num;
    num = excA[i] * xpA[i];
    num = fmaf(exmA[i], xmA[i], num);
    num = fmaf(eycA[i], ypA[i], num);
    num = fmaf(eymA[i], ymA[i], num);
    num = fmaf(ezA[i + 1], pz[i + 2], num);
    num = fmaf(ezA[i],     pz[i],     num);
    o[i] = fmaf(rdA[i], num, rqA[i]);
  }
  if (FINAL) {
    ((float4*)(pout_f + cb0 + v))[0] = make_float4(o[0], o[1], o[2], o[3]);
  } else {
    ((ushort4*)(pout + cb0 + v))[0] =
        make_ushort4(f2bf(o[0]), f2bf(o[1]), f2bf(o[2]), f2bf(o[3]));
  }
}

// ---------------------------------------------------------------------------
// Fallback fp32 Jacobi (if ws too small)
// ---------------------------------------------------------------------------
__global__ __launch_bounds__(256) void jacobi_kernel(
    const float* __restrict__ phi_in, float* __restrict__ phi_out,
    const float* __restrict__ eps, const float* __restrict__ rhs, int B) {
  int i = blockIdx.x * blockDim.x + threadIdx.x;
  if (i >= B * MCELLS) return;
  int b = i >> 21;
  int v = i & (MCELLS - 1);
  int z = v & 127;
  int y = (v >> 7) & 127;
  int x = v >> 14;

  const float* ex = eps + (size_t)(b * 4 + 0) * MCELLS;
  const float* ey = eps + (size_t)(b * 4 + 1) * MCELLS;
  const float* ez = eps + (size_t)(b * 4 + 2) * MCELLS;
  const float* lm = eps + (size_t)(b * 4 + 3) * MCELLS;
  const float* p  = phi_in + (size_t)b * MCELLS;

  float exc = ex[v], eyc = ey[v], ezc = ez[v];
  float exm = (x > 0) ? ex[v - BOX * BOX] : 0.0f;
  float eym = (y > 0) ? ey[v - BOX]       : 0.0f;
  float ezm = (z > 0) ? ez[v - 1]         : 0.0f;

  float num = rhs[i];
  num += (x < BOX - 1) ? exc * p[v + BOX * BOX] : 0.0f;
  num += (x > 0)       ? exm * p[v - BOX * BOX] : 0.0f;
  num += (y < BOX - 1) ? eyc * p[v + BOX]       : 0.0f;
  num += (y > 0)       ? eym * p[v - BOX]       : 0.0f;
  num += (z < BOX - 1) ? ezc * p[v + 1]         : 0.0f;
  num += (z > 0)       ? ezm * p[v - 1]         : 0.0f;

  float den = exc + exm + eyc + eym + ezc + ezm + 0.106f * lm[v];
  phi_out[i] = num / den;
}

// ---------------------------------------------------------------------------
extern "C" void kernel_launch(void* const* d_in, const int* in_sizes, int n_in,
                              void* d_out, int out_size, void* d_ws,
                              size_t ws_size, hipStream_t stream) {
  const float* coords    = (const float*)d_in[0];
  const float* params    = (const float*)d_in[1];
  const int*   num_atoms = (const int*)d_in[2];

  const int B = in_sizes[2];
  const int N = in_sizes[1] / (2 * B);

  float* out = (float*)d_out;
  float* q   = out;                            // (B, M)
  float* eps = out + (size_t)B * MCELLS;       // (B, 4, M)
  float* phi = out + (size_t)B * MCELLS * 5;   // (B, M)

  const size_t BM = (size_t)B * MCELLS;
  const size_t need = BM * 14;  // 7 u16 arrays of B*M

  // ws carve-up (u16 arrays): phiA, phiB, exb, eyb, ezb, rdn, rq2
  u16* phiA = (u16*)d_ws;
  u16* phiB = phiA + BM;
  u16* exb  = phiB + BM;
  u16* eyb  = exb + BM;
  u16* ezb  = eyb + BM;
  u16* rdn  = ezb + BM;
  u16* rq2  = rdn + BM;

  const bool bf16_path = (ws_size >= need);

  // q is a scatter accumulator -> zero it (eps/phi are fully overwritten
  // on the bf16 path; fallback also memsets phi).
  hipMemsetAsync(q, 0, sizeof(float) * BM, stream);

  // eps gather (writes fp32 eps + bf16 ex/ey/ez packs)
  {
    dim3 grid(16, 16, 8 * B);
    eps_gather_kernel<<<grid, 256, 0, stream>>>(
        coords, params, num_atoms, eps,
        bf16_path ? exb : (u16*)d_ws,   // harmless dump space on fallback
        bf16_path ? eyb : (u16*)d_ws,
        bf16_path ? ezb : (u16*)d_ws, N);
  }

  q_scatter_kernel<<<(B * N + 255) / 256, 256, 0, stream>>>(
      coords, params, num_atoms, q, N, B);

  if (bf16_path) {
    int t4 = (int)(BM / 4);
    int blocks = (t4 + 255) / 256;
    // sweep 1 folded into prep (phi0 = 0 -> phi1 = rhs/den = rq2)
    prep_kernel<<<blocks, 256, 0, stream>>>(eps, q, rdn, rq2, phiA, B);
    // sweeps 2..29 (28 sweeps) bf16 ping-pong A->B->A, ends in A
    u16* pa = phiA;
    u16* pb = phiB;
    for (int it = 0; it < 28; ++it) {
      jacobi_sweep_kernel<false><<<blocks, 256, 0, stream>>>(
          pa, pb, nullptr, exb, eyb, ezb, rdn, rq2, B);
      u16* tmp = pa; pa = pb; pb = tmp;
    }
    // sweep 30: fp32 write to d_out
    jacobi_sweep_kernel<true><<<blocks, 256, 0, stream>>>(
        pa, nullptr, phi, exb, eyb, ezb, rdn, rq2, B);
  } else {
    // fp32 fallback: phi0 = 0, 30 sweeps ping-pong out<->ws
    hipMemsetAsync(phi, 0, sizeof(float) * BM, stream);
    float* pa = phi;
    float* pb = (float*)d_ws;
    int total = (int)BM;
    for (int it = 0; it < 30; ++it) {
      jacobi_kernel<<<(total + 255) / 256, 256, 0, stream>>>(pa, pb, eps, q, B);
      float* tmp = pa; pa = pb; pb = tmp;
    }
  }
}